// Round 6
// baseline (383.838 us; speedup 1.0000x reference)
//
#include <hip/hip_runtime.h>
#include <hip/hip_bf16.h>
#include <math.h>

// B=16, T=16, O=10, L=160, d=768, heads=12, dh=64, H=W=14, Tr=2.
// Out: (16, 8*196, 768) fp32.

#define BATCH 16
#define TT    16
#define OO    10
#define LL    160
#define BL    2560
#define DD    768
#define NH    12
#define DH    64
#define GH    14
#define GW    14
#define TGRP  8

typedef unsigned short ushort_t;
typedef __attribute__((ext_vector_type(8))) __bf16 bf16x8;
typedef __attribute__((ext_vector_type(4))) float f32x4;

__device__ __forceinline__ ushort_t f2bf(float f) {
    unsigned int u = __float_as_uint(f);
    u += 0x7fffu + ((u >> 16) & 1u);         // RNE
    return (ushort_t)(u >> 16);
}

// ---------------------------------------------------------------------------
// 0) weight convert+transpose: W[K][N] fp32 -> Wt[N][K] bf16
// ---------------------------------------------------------------------------
__global__ __launch_bounds__(256)
void transpose_w(const float* __restrict__ W, ushort_t* __restrict__ Wt, int K, int N)
{
    __shared__ float s[32][33];
    const int n0 = blockIdx.x * 32, k0 = blockIdx.y * 32;
    const int tx = threadIdx.x & 31, ty = threadIdx.x >> 5;   // ty 0..7
#pragma unroll
    for (int r = 0; r < 4; ++r)
        s[ty + r * 8][tx] = W[(size_t)(k0 + ty + r * 8) * N + n0 + tx];
    __syncthreads();
#pragma unroll
    for (int r = 0; r < 4; ++r)
        Wt[(size_t)(n0 + ty + r * 8) * K + k0 + tx] = f2bf(s[tx][ty + r * 8]);
}

// ---------------------------------------------------------------------------
// 1a) box hidden: h = relu(box @ w1) -> bf16 [2560][384]
// ---------------------------------------------------------------------------
__global__ __launch_bounds__(256)
void box_h(const float* __restrict__ box, const float* __restrict__ w1,
           ushort_t* __restrict__ h)
{
    const int idx = blockIdx.x * 256 + threadIdx.x;     // 0..983039
    const int r = idx / 384, j = idx - r * 384;
    const float* bx = box + (size_t)r * 4;
    float v = bx[0] * w1[j] + bx[1] * w1[384 + j] +
              bx[2] * w1[768 + j] + bx[3] * w1[1152 + j];
    h[idx] = f2bf(fmaxf(v, 0.f));
}

// ---------------------------------------------------------------------------
// 2) LayerNorm -> bf16 output
// ---------------------------------------------------------------------------
__global__ __launch_bounds__(256)
void ln_kernel(const float* __restrict__ in, const float* __restrict__ g,
               const float* __restrict__ bvec, ushort_t* __restrict__ out)
{
    const int r = blockIdx.x;
    const int tid = threadIdx.x;
    const float* row = in + (size_t)r * DD;
    float v0 = row[tid], v1 = row[tid + 256], v2 = row[tid + 512];
    float s  = v0 + v1 + v2;
    float s2 = v0 * v0 + v1 * v1 + v2 * v2;
#pragma unroll
    for (int off = 32; off > 0; off >>= 1) {
        s  += __shfl_down(s, off);
        s2 += __shfl_down(s2, off);
    }
    __shared__ float red[8];
    int wave = tid >> 6, lane = tid & 63;
    if (lane == 0) { red[wave] = s; red[wave + 4] = s2; }
    __syncthreads();
    s  = red[0] + red[1] + red[2] + red[3];
    s2 = red[4] + red[5] + red[6] + red[7];
    float mu  = s * (1.f / DD);
    float var = s2 * (1.f / DD) - mu * mu;
    float inv = rsqrtf(var + 1e-5f);
    ushort_t* op = out + (size_t)r * DD;
    op[tid]       = f2bf((v0 - mu) * inv * g[tid]       + bvec[tid]);
    op[tid + 256] = f2bf((v1 - mu) * inv * g[tid + 256] + bvec[tid + 256]);
    op[tid + 512] = f2bf((v2 - mu) * inv * g[tid + 512] + bvec[tid + 512]);
}

// ---------------------------------------------------------------------------
// 3) register-fragment bf16 MFMA GEMM: 256 thr = 4 waves, block tile
//    64 rows x 256 cols (each wave a private 64x64 tile). All 4 waves load
//    IDENTICAL A fragments -> waves 1-3 hit L1 (per-CU); no LDS, no barriers.
//    2-deep in-register pipeline (Kper multiple of 64).
//    A[M][K] row-major bf16 (lda), Bt[N][K] row-major bf16 (ldb).
//    MODE 1: Cf += acc + bias (atomicAdd when SPLIT>1; bias only slice 0)
//    MODE 2: Cb = bf16(gelu(acc+bias))
//    MODE 3: Cb = bf16(acc)
//    MODE 4: Cf = relu(acc) + cat[(row%160)][col]
// ---------------------------------------------------------------------------
#define LOADF(aa, bb, kk)                                                        \
    _Pragma("unroll")                                                            \
    for (int i = 0; i < 4; ++i) {                                                \
        aa[i] = *reinterpret_cast<const bf16x8*>(ap + (size_t)(i * 16) * lda + (kk)); \
        bb[i] = *reinterpret_cast<const bf16x8*>(bp + (size_t)(i * 16) * ldb + (kk)); \
    }
#define MFMA16(aa, bb)                                                           \
    _Pragma("unroll")                                                            \
    for (int i = 0; i < 4; ++i)                                                  \
        _Pragma("unroll")                                                        \
        for (int j = 0; j < 4; ++j)                                              \
            acc[i][j] = __builtin_amdgcn_mfma_f32_16x16x32_bf16(aa[i], bb[j], acc[i][j], 0, 0, 0);

template <int MODE, int SPLIT>
__global__ __launch_bounds__(256)
void gemm_rf(const ushort_t* __restrict__ A, int lda,
             const ushort_t* __restrict__ Bt, int ldb,
             const float* __restrict__ bias, const float* __restrict__ cat,
             float* __restrict__ Cf, ushort_t* __restrict__ Cb,
             int ldc, int K)
{
    const int tid = threadIdx.x;
    const int wave = tid >> 6, lane = tid & 63;
    const int l16 = lane & 15, quad = lane >> 4;
    const int row0 = blockIdx.y * 64;
    const int col0 = blockIdx.x * 256 + wave * 64;
    const int Kper = K / SPLIT;
    const int k0 = blockIdx.z * Kper;

    const ushort_t* ap = A  + (size_t)(row0 + l16) * lda + k0 + quad * 8;
    const ushort_t* bp = Bt + (size_t)(col0 + l16) * ldb + k0 + quad * 8;

    f32x4 acc[4][4];
#pragma unroll
    for (int i = 0; i < 4; ++i)
#pragma unroll
        for (int j = 0; j < 4; ++j) {
            acc[i][j][0] = 0.f; acc[i][j][1] = 0.f;
            acc[i][j][2] = 0.f; acc[i][j][3] = 0.f;
        }

    bf16x8 a0[4], b0[4], a1[4], b1[4];
    LOADF(a0, b0, 0)
    int kt = 0;
    for (; kt + 64 < Kper; kt += 64) {
        LOADF(a1, b1, kt + 32)
        MFMA16(a0, b0)
        LOADF(a0, b0, kt + 64)
        MFMA16(a1, b1)
    }
    LOADF(a1, b1, kt + 32)
    MFMA16(a0, b0)
    MFMA16(a1, b1)

    // epilogue: C/D layout col=lane&15, row=(lane>>4)*4+reg
    const int q4 = quad * 4;
#pragma unroll
    for (int i = 0; i < 4; ++i)
#pragma unroll
        for (int j = 0; j < 4; ++j) {
            const int gcol = col0 + j * 16 + l16;
            const float bj = (MODE == 1 || MODE == 2)
                               ? ((SPLIT == 1 || blockIdx.z == 0) ? bias[gcol] : 0.f)
                               : 0.f;
#pragma unroll
            for (int r = 0; r < 4; ++r) {
                const int grow = row0 + i * 16 + q4 + r;
                const size_t idx = (size_t)grow * ldc + gcol;
                const float v = acc[i][j][r];
                if (MODE == 1) {
                    if (SPLIT > 1) atomicAdd(&Cf[idx], v + bj);
                    else           Cf[idx] += v + bj;
                } else if (MODE == 2) {
                    const float u = v + bj;
                    Cb[idx] = f2bf(0.5f * u * (1.f + erff(u * 0.70710678118654752f)));
                } else if (MODE == 3) {
                    Cb[idx] = f2bf(v);
                } else {
                    Cf[idx] = fmaxf(v, 0.f) + cat[(size_t)(grow % LL) * DD + gcol];
                }
            }
        }
}

// ---------------------------------------------------------------------------
// 4) MFMA attention: block per (b,head), 5 waves; output written back into
//    the (dead) q-slot of qkv. Frag layouts HW-verified by gemm path.
// ---------------------------------------------------------------------------
#define KS_STRIDE 72
#define VT_STRIDE 168
__global__ __launch_bounds__(320)
void attention_mfma(ushort_t* __restrict__ qkv)
{
    __shared__ ushort_t Ks[160 * KS_STRIDE];
    __shared__ ushort_t Vt[64 * VT_STRIDE];
    __shared__ ushort_t Pb[5][32 * VT_STRIDE];

    const int b  = blockIdx.x / NH;
    const int hh = blockIdx.x % NH;
    ushort_t* basew = qkv + (size_t)b * LL * (3 * DD) + hh * DH;
    const ushort_t* base = basew;
    const int tid  = threadIdx.x;
    const int wave = tid >> 6, lane = tid & 63;
    const int l16 = lane & 15, quad = lane >> 4;

    // ---- stage K rows and V transposed ----
#pragma unroll
    for (int it = 0; it < 4; ++it) {
        int idx = tid + it * 320;                 // 0..1279
        int l = idx >> 3, c8 = (idx & 7) * 8;
        uint4 kv = *(const uint4*)(base + (size_t)l * (3 * DD) + DD + c8);
        *(uint4*)&Ks[l * KS_STRIDE + c8] = kv;
        uint4 vv = *(const uint4*)(base + (size_t)l * (3 * DD) + 2 * DD + c8);
        ushort_t e[8];
        *(uint4*)e = vv;
#pragma unroll
        for (int i = 0; i < 8; ++i)
            Vt[(c8 + i) * VT_STRIDE + l] = e[i];
    }

    // ---- Q fragments straight from global ----
    const int q0 = wave * 32;
    bf16x8 qf[2][2];
#pragma unroll
    for (int t = 0; t < 2; ++t)
#pragma unroll
        for (int k = 0; k < 2; ++k)
            qf[t][k] = *reinterpret_cast<const bf16x8*>(
                base + (size_t)(q0 + t * 16 + l16) * (3 * DD) + k * 32 + quad * 8);

    __syncthreads();

    // ---- S = QK^T ----
    f32x4 S0[10], S1[10];
#pragma unroll
    for (int nt = 0; nt < 10; ++nt) {
        f32x4 z = {0.f, 0.f, 0.f, 0.f};
        const ushort_t* kb = &Ks[(nt * 16 + l16) * KS_STRIDE + quad * 8];
        bf16x8 kf0 = *reinterpret_cast<const bf16x8*>(kb);
        bf16x8 kf1 = *reinterpret_cast<const bf16x8*>(kb + 32);
        f32x4 a0 = __builtin_amdgcn_mfma_f32_16x16x32_bf16(qf[0][0], kf0, z, 0, 0, 0);
        S0[nt]   = __builtin_amdgcn_mfma_f32_16x16x32_bf16(qf[0][1], kf1, a0, 0, 0, 0);
        f32x4 a1 = __builtin_amdgcn_mfma_f32_16x16x32_bf16(qf[1][0], kf0, z, 0, 0, 0);
        S1[nt]   = __builtin_amdgcn_mfma_f32_16x16x32_bf16(qf[1][1], kf1, a1, 0, 0, 0);
    }

    // ---- softmax per tile; P (already / l) to wave-private LDS ----
#pragma unroll
    for (int t = 0; t < 2; ++t) {
        f32x4* S = t ? S1 : S0;
        float mrow[4] = {-1e30f, -1e30f, -1e30f, -1e30f};
#pragma unroll
        for (int nt = 0; nt < 10; ++nt)
#pragma unroll
            for (int r = 0; r < 4; ++r) {
                S[nt][r] *= 0.125f;
                mrow[r] = fmaxf(mrow[r], S[nt][r]);
            }
#pragma unroll
        for (int r = 0; r < 4; ++r) {
            mrow[r] = fmaxf(mrow[r], __shfl_xor(mrow[r], 1));
            mrow[r] = fmaxf(mrow[r], __shfl_xor(mrow[r], 2));
            mrow[r] = fmaxf(mrow[r], __shfl_xor(mrow[r], 4));
            mrow[r] = fmaxf(mrow[r], __shfl_xor(mrow[r], 8));
        }
        float lsum[4] = {0.f, 0.f, 0.f, 0.f};
#pragma unroll
        for (int nt = 0; nt < 10; ++nt)
#pragma unroll
            for (int r = 0; r < 4; ++r) {
                float e = __expf(S[nt][r] - mrow[r]);
                S[nt][r] = e;
                lsum[r] += e;
            }
#pragma unroll
        for (int r = 0; r < 4; ++r) {
            lsum[r] += __shfl_xor(lsum[r], 1);
            lsum[r] += __shfl_xor(lsum[r], 2);
            lsum[r] += __shfl_xor(lsum[r], 4);
            lsum[r] += __shfl_xor(lsum[r], 8);
            lsum[r] = 1.f / lsum[r];
        }
#pragma unroll
        for (int nt = 0; nt < 10; ++nt)
#pragma unroll
            for (int r = 0; r < 4; ++r)
                Pb[wave][(t * 16 + quad * 4 + r) * VT_STRIDE + nt * 16 + l16] =
                    f2bf(S[nt][r] * lsum[r]);
    }
    asm volatile("s_waitcnt lgkmcnt(0)" ::: "memory");   // wave-local P write->read

    // ---- O^T = Vt . P^T ; write into q-slot ----
#pragma unroll
    for (int dt = 0; dt < 4; ++dt) {
        f32x4 o0 = {0.f, 0.f, 0.f, 0.f}, o1 = {0.f, 0.f, 0.f, 0.f};
#pragma unroll
        for (int ks = 0; ks < 5; ++ks) {
            bf16x8 vf = *reinterpret_cast<const bf16x8*>(
                &Vt[(dt * 16 + l16) * VT_STRIDE + ks * 32 + quad * 8]);
            bf16x8 p0 = *reinterpret_cast<const bf16x8*>(
                &Pb[wave][(l16) * VT_STRIDE + ks * 32 + quad * 8]);
            bf16x8 p1 = *reinterpret_cast<const bf16x8*>(
                &Pb[wave][(16 + l16) * VT_STRIDE + ks * 32 + quad * 8]);
            o0 = __builtin_amdgcn_mfma_f32_16x16x32_bf16(vf, p0, o0, 0, 0, 0);
            o1 = __builtin_amdgcn_mfma_f32_16x16x32_bf16(vf, p1, o1, 0, 0, 0);
        }
#pragma unroll
        for (int t = 0; t < 2; ++t) {
            f32x4 o = t ? o1 : o0;
            ushort_t pk[4];
#pragma unroll
            for (int r = 0; r < 4; ++r) pk[r] = f2bf(o[r]);
            ushort_t* dst = basew + (size_t)(q0 + t * 16 + l16) * (3 * DD) +
                            dt * 16 + quad * 4;
            *(uint2*)dst = *(const uint2*)pk;
        }
    }
}

// ---------------------------------------------------------------------------
// 5) mask + grid aggregation + temporal mean
// ---------------------------------------------------------------------------
__global__ __launch_bounds__(256)
void mask_grid(const float* __restrict__ box, const float* __restrict__ feats,
               float* __restrict__ out)
{
    const int hw = blockIdx.x;
    const int g  = blockIdx.y;
    const int b  = blockIdx.z;
    const int hh = hw / GW, w = hw % GW;
    const float cy = (hh + 0.5f) / (float)GH;
    const float cx = (w  + 0.5f) / (float)GW;
    const int tid = threadIdx.x;

    __shared__ float flg[20];
    if (tid < 20) {
        int t = g * 2 + tid / OO, o = tid % OO;
        const float* bx = box + (size_t)((b * TT + t) * OO + o) * 4;
        float x1 = fminf(bx[0], bx[2]), x2 = fmaxf(bx[0], bx[2]);
        float y1 = fminf(bx[1], bx[3]), y2 = fmaxf(bx[1], bx[3]);
        flg[tid] = (cy >= y1 && cy <= y2 && cx >= x1 && cx <= x2) ? 1.f : 0.f;
    }
    __syncthreads();

    float a0 = 0.f, a1 = 0.f, a2 = 0.f;
#pragma unroll
    for (int p = 0; p < 20; ++p) {
        if (flg[p] != 0.f) {
            int r = (b * TT + g * 2 + p / OO) * OO + (p % OO);
            const float* f = feats + (size_t)r * DD;
            a0 += f[tid]; a1 += f[tid + 256]; a2 += f[tid + 512];
        }
    }
    float* op = out + ((size_t)b * (TGRP * GH * GW) + g * (GH * GW) + hw) * DD;
    op[tid]       = a0 * 0.5f;
    op[tid + 256] = a1 * 0.5f;
    op[tid + 512] = a2 * 0.5f;
}

// ---------------------------------------------------------------------------
extern "C" void kernel_launch(void* const* d_in, const int* in_sizes, int n_in,
                              void* d_out, int out_size, void* d_ws, size_t ws_size,
                              hipStream_t stream)
{
    const float* box  = (const float*)d_in[0];
    const float* cat  = (const float*)d_in[1];
    const float* w1   = (const float*)d_in[2];
    const float* w2   = (const float*)d_in[3];
    const float* ln1g = (const float*)d_in[4];
    const float* ln1b = (const float*)d_in[5];
    const float* wqkv = (const float*)d_in[6];
    const float* wo   = (const float*)d_in[7];
    const float* bo   = (const float*)d_in[8];
    const float* ln2g = (const float*)d_in[9];
    const float* ln2b = (const float*)d_in[10];
    const float* wfc1 = (const float*)d_in[11];
    const float* bfc1 = (const float*)d_in[12];
    const float* wfc2 = (const float*)d_in[13];
    const float* bfc2 = (const float*)d_in[14];
    float* out = (float*)d_out;

    // workspace layout (byte offsets, 16B aligned), total 44,236,800 B
    char* wsb = (char*)d_ws;
    float*    x     = (float*)   (wsb + 0);           //  7,864,320 (2560x768 f32)
    ushort_t* qkvb  = (ushort_t*)(wsb + 7864320);     // 15,728,640 (qkv 2560x2304 / fc1 2560x3072 overlay)
    ushort_t* fc1b  = qkvb;
    ushort_t* hnb   = (ushort_t*)(wsb + 23592960);    //  3,932,160 (2560x768)
    ushort_t* wqkvT = (ushort_t*)(wsb + 27525120);    //  3,538,944 (2304x768)
    ushort_t* woT   = (ushort_t*)(wsb + 31064064);    //  1,179,648 (768x768)
    ushort_t* wfc1T = (ushort_t*)(wsb + 32243712);    //  4,718,592 (3072x768)
    ushort_t* wfc2T = (ushort_t*)(wsb + 36962304);    //  4,718,592 (768x3072)
    ushort_t* w2T   = (ushort_t*)(wsb + 41680896);    //    589,824 (768x384)
    ushort_t* h     = (ushort_t*)(wsb + 42270720);    //  1,966,080 (2560x384)

    transpose_w<<<dim3(2304 / 32, 768 / 32), 256, 0, stream>>>(wqkv, wqkvT, 768, 2304);
    transpose_w<<<dim3(768 / 32, 768 / 32), 256, 0, stream>>>(wo, woT, 768, 768);
    transpose_w<<<dim3(3072 / 32, 768 / 32), 256, 0, stream>>>(wfc1, wfc1T, 768, 3072);
    transpose_w<<<dim3(768 / 32, 3072 / 32), 256, 0, stream>>>(wfc2, wfc2T, 3072, 768);
    transpose_w<<<dim3(768 / 32, 384 / 32), 256, 0, stream>>>(w2, w2T, 384, 768);

    box_h<<<BL * 384 / 256, 256, 0, stream>>>(box, w1, h);
    // x = relu(h @ w2) + cat[t,o]   (N=768 -> 3 x-blocks of 256 cols)
    gemm_rf<4, 1><<<dim3(3, 40, 1), 256, 0, stream>>>(h, 384, w2T, 384, nullptr, cat,
                                                      x, nullptr, DD, 384);
    ln_kernel<<<BL, 256, 0, stream>>>(x, ln1g, ln1b, hnb);
    gemm_rf<3, 1><<<dim3(9, 40, 1), 256, 0, stream>>>(hnb, DD, wqkvT, DD, nullptr, nullptr,
                                                      nullptr, qkvb, 3 * DD, DD);
    attention_mfma<<<BATCH * NH, 320, 0, stream>>>(qkvb);
    // x += attn_out @ wo + bo   (A = q-slot of qkv, lda = 2304; split-K=2)
    gemm_rf<1, 2><<<dim3(3, 40, 2), 256, 0, stream>>>(qkvb, 3 * DD, woT, DD, bo, nullptr,
                                                      x, nullptr, DD, DD);
    ln_kernel<<<BL, 256, 0, stream>>>(x, ln2g, ln2b, hnb);
    gemm_rf<2, 1><<<dim3(12, 40, 1), 256, 0, stream>>>(hnb, DD, wfc1T, DD, bfc1, nullptr,
                                                       nullptr, fc1b, 4 * DD, DD);
    // x += gelu_fc1 @ wfc2 + bfc2  (split-K=2)
    gemm_rf<1, 2><<<dim3(3, 40, 2), 256, 0, stream>>>(fc1b, 4 * DD, wfc2T, 4 * DD, bfc2, nullptr,
                                                      x, nullptr, DD, 4 * DD);
    mask_grid<<<dim3(GH * GW, TGRP, BATCH), 256, 0, stream>>>(box, x, out);
}